// Round 4
// baseline (116.829 us; speedup 1.0000x reference)
//
#include <hip/hip_runtime.h>

// Problem constants (B,C,T,H,HI) = (256, 64, 512, 8, 3)
constexpr int Tn = 512;
constexpr int Cn = 64;
constexpr int NS = 16384;   // sequences = B*C; acc planes are [t][seq]

typedef float f2 __attribute__((ext_vector_type(2)));

// DPP move with compile-time control (quad_perm patterns).
template<int CTRL>
__device__ __forceinline__ float dppf(float v) {
    int i = __builtin_bit_cast(int, v);
    i = __builtin_amdgcn_mov_dpp(i, CTRL, 0xF, 0xF, true);
    return __builtin_bit_cast(float, i);
}
// Rotate packed pair within quad: lane q gets lane (q+1)&3's value.
__device__ __forceinline__ f2 rot1(f2 v) {
    f2 r; r.x = dppf<0x39>(v.x); r.y = dppf<0x39>(v.y); return r;
}

// One recurrence step for the quad decomposition. Updates h (f2, rows 2q,2q+1),
// stores the quad-summed U·h to *op, advances op by SGN NS.
#define QSTEP(xv, mv, dv, SGN) do {                                   \
    f2 hr = h;                                                        \
    f2 a0 = cbp + Vp0 * (xv);                                         \
    f2 a1 = Vp1 * (mv);                                               \
    a0 += Vp2 * (dv);                                                 \
    a0 += WA0 * hr.x;  a1 += WB0 * hr.y;                              \
    hr = rot1(hr);                                                    \
    a0 += WA1 * hr.x;  a1 += WB1 * hr.y;                              \
    hr = rot1(hr);                                                    \
    a0 += WA2 * hr.x;  a1 += WB2 * hr.y;                              \
    hr = rot1(hr);                                                    \
    a0 += WA3 * hr.x;  a1 += WB3 * hr.y;                              \
    f2 hn = a0 + a1;                                                  \
    hn.x = fmaxf(hn.x, 0.f); hn.y = fmaxf(hn.y, 0.f);                 \
    h = hn;                                                           \
    float pdv = Up.x * hn.x + Up.y * hn.y;                            \
    pdv += dppf<0xB1>(pdv);                                           \
    pdv += dppf<0x4E>(pdv);                                           \
    *op = pdv;                                                        \
    op SGN NS;                                                        \
} while (0)

// Forward 4-step group: carry holds u=4g-1 sample; float4 covers u=4g..4g+3.
#define GRP_F(X4, M4, D4) do {                                        \
    QSTEP(cx, cm, cd, +=);                                            \
    QSTEP((X4).x, (M4).x, (D4).x, +=);                                \
    QSTEP((X4).y, (M4).y, (D4).y, +=);                                \
    QSTEP((X4).z, (M4).z, (D4).z, +=);                                \
    cx = (X4).w; cm = (M4).w; cd = (D4).w;                            \
} while (0)

// Backward 4-step group: carry holds u=512-4g sample; float4 covers u=508-4g..511-4g.
#define GRP_B(X4, M4, D4) do {                                        \
    QSTEP(cx, cm, cd, -=);                                            \
    QSTEP((X4).w, (M4).w, (D4).w, -=);                                \
    QSTEP((X4).z, (M4).z, (D4).z, -=);                                \
    QSTEP((X4).y, (M4).y, (D4).y, -=);                                \
    cx = (X4).x; cm = (M4).x; cd = (D4).x;                            \
} while (0)

// Bidirectional per-channel RNN scan, quad decomposition with rotation:
// 4 lanes per (sequence, direction); lane q owns hidden rows {2q,2q+1} as one
// f2. Cross-lane state via 3 quad rotations (6 DPP/step). Packed fp32 math.
// Writes acc[t*NS + seq] = U-half · h(t), t-major.
__global__ __launch_bounds__(256, 2) void mrnn_scan(
    const float* __restrict__ x, const float* __restrict__ m, const float* __restrict__ d,
    const float* __restrict__ Wf, const float* __restrict__ Vf, const float* __restrict__ cf,
    const float* __restrict__ Wb, const float* __restrict__ Vb, const float* __restrict__ cbk,
    const float* __restrict__ U, float* __restrict__ accF, float* __restrict__ accB)
{
    const int g   = blockIdx.x * blockDim.x + threadIdx.x;
    const int q   = g & 3;          // lane-in-quad: owns rows 2q, 2q+1
    const int sd  = g >> 2;         // (dir, seq)
    const int dir = sd >> 14;       // 0 = forward, 1 = backward
    const int seq = sd & 16383;     // b*64 + c
    const int c   = seq & 63;
    const long base = (long)seq * Tn;

    const float* W  = dir ? Wb  : Wf;
    const float* V  = dir ? Vb  : Vf;
    const float* cc = dir ? cbk : cf;

    const int r0 = 2*q, r1 = 2*q + 1;

    // Rotation-permuted packed weights: rotation j sees h of lane (q+j)&3,
    // i.e. rows 2s,2s+1 with s=(q+j)&3. WAj multiplies hr.x, WBj multiplies hr.y.
    f2 WA0, WA1, WA2, WA3, WB0, WB1, WB2, WB3, Vp0, Vp1, Vp2, cbp, Up;
    {
        const float* Wc = W + c*64;
        int col;
        col = 2*((q+0)&3);
        WA0 = f2{Wc[r0*8+col],   Wc[r1*8+col]};
        WB0 = f2{Wc[r0*8+col+1], Wc[r1*8+col+1]};
        col = 2*((q+1)&3);
        WA1 = f2{Wc[r0*8+col],   Wc[r1*8+col]};
        WB1 = f2{Wc[r0*8+col+1], Wc[r1*8+col+1]};
        col = 2*((q+2)&3);
        WA2 = f2{Wc[r0*8+col],   Wc[r1*8+col]};
        WB2 = f2{Wc[r0*8+col+1], Wc[r1*8+col+1]};
        col = 2*((q+3)&3);
        WA3 = f2{Wc[r0*8+col],   Wc[r1*8+col]};
        WB3 = f2{Wc[r0*8+col+1], Wc[r1*8+col+1]};
    }
    Vp0 = f2{V[c*24 + r0*3 + 0], V[c*24 + r1*3 + 0]};
    Vp1 = f2{V[c*24 + r0*3 + 1], V[c*24 + r1*3 + 1]};
    Vp2 = f2{V[c*24 + r0*3 + 2], V[c*24 + r1*3 + 2]};
    cbp = f2{cc[c*8 + r0], cc[c*8 + r1]};
    Up  = f2{U[c*16 + dir*8 + r0], U[c*16 + dir*8 + r1]};

    f2 h = {0.f, 0.f};
    float cx, cm, cd;
    const float4* x4 = (const float4*)(x + base);
    const float4* m4 = (const float4*)(m + base);
    const float4* d4 = (const float4*)(d + base);
    float* op = (dir ? accB : accF) + seq;   // element stride NS per time step

    if (dir == 0) {
        // forward: step t uses u = max(t-1,0); group g covers t=4g..4g+3
        float4 Ax = x4[0], Am = m4[0], Ad = d4[0];
        float4 Bx = x4[1], Bm = m4[1], Bd = d4[1];
        cx = Ax.x; cm = Am.x; cd = Ad.x;       // u=0 for t=0
        #pragma unroll 1
        for (int i = 0; i < 63; ++i) {
            float4 Txq = x4[2*i+2], Tmq = m4[2*i+2], Tdq = d4[2*i+2];
            GRP_F(Ax, Am, Ad);                 // group 2i
            float4 Uxq = x4[2*i+3], Umq = m4[2*i+3], Udq = d4[2*i+3];
            GRP_F(Bx, Bm, Bd);                 // group 2i+1
            Ax = Txq; Am = Tmq; Ad = Tdq;
            Bx = Uxq; Bm = Umq; Bd = Udq;
        }
        GRP_F(Ax, Am, Ad);                     // group 126
        GRP_F(Bx, Bm, Bd);                     // group 127
    } else {
        // backward: pos descends 511..0; group g covers pos 511-4g..508-4g,
        // uses float4 block 127-g (u = pos+1, clamped at 511 for pos=511)
        op += 511 * NS;
        float4 Ax = x4[127], Am = m4[127], Ad = d4[127];
        float4 Bx = x4[126], Bm = m4[126], Bd = d4[126];
        cx = Ax.w; cm = Am.w; cd = Ad.w;       // u=511 for pos=511 (s=0)
        #pragma unroll 1
        for (int i = 0; i < 63; ++i) {
            float4 Txq = x4[125-2*i], Tmq = m4[125-2*i], Tdq = d4[125-2*i];
            GRP_B(Ax, Am, Ad);                 // group 2i
            float4 Uxq = x4[124-2*i], Umq = m4[124-2*i], Udq = d4[124-2*i];
            GRP_B(Bx, Bm, Bd);                 // group 2i+1
            Ax = Txq; Am = Tmq; Ad = Tdq;
            Bx = Uxq; Bm = Umq; Bd = Udq;
        }
        GRP_B(Ax, Am, Ad);                     // group 126
        GRP_B(Bx, Bm, Bd);                     // group 127
    }
}

// Combine + cross-channel bottleneck MLP. One thread per (b,t).
// x_est = relu(accF + accB + c0); h(3) = relu(V1·x_est + V2·m + Uz·x + U_b);
// out = W_w·h + W_b.
__global__ __launch_bounds__(256, 2) void mrnn_mix(
    const float* __restrict__ x, const float* __restrict__ m,
    const float* __restrict__ accF, const float* __restrict__ accB,
    const float* __restrict__ c0, const float* __restrict__ V1w,
    const float* __restrict__ V2w, const float* __restrict__ Uw,
    const float* __restrict__ Ub, const float* __restrict__ Ww,
    const float* __restrict__ Wbias, float* __restrict__ out)
{
    const int bt = blockIdx.x * 256 + threadIdx.x;   // 0..131071
    const int b = bt >> 9;
    const int t = bt & 511;

    const float4* aF4 = (const float4*)(accF + (size_t)t * NS + b * Cn);
    const float4* aB4 = (const float4*)(accB + (size_t)t * NS + b * Cn);
    const size_t xb = (size_t)b * (Cn * Tn) + t;

    float h0 = Ub[0], h1 = Ub[1], h2 = Ub[2];
    #pragma unroll
    for (int c4 = 0; c4 < 16; ++c4) {
        const float4 fa = aF4[c4];
        const float4 fb = aB4[c4];
        const float fav[4] = {fa.x, fa.y, fa.z, fa.w};
        const float fbv[4] = {fb.x, fb.y, fb.z, fb.w};
        #pragma unroll
        for (int j = 0; j < 4; ++j) {
            const int cch = 4*c4 + j;
            const float xe = fmaxf(fav[j] + fbv[j] + c0[cch], 0.f);
            const float mv = m[xb + (size_t)cch * Tn];
            const float xv = x[xb + (size_t)cch * Tn];
            const float u0 = (cch == 0) ? 0.f : Uw[0*Cn + cch];
            const float u1 = (cch == 1) ? 0.f : Uw[1*Cn + cch];
            const float u2 = (cch == 2) ? 0.f : Uw[2*Cn + cch];
            h0 += V1w[0*Cn + cch]*xe + V2w[0*Cn + cch]*mv + u0*xv;
            h1 += V1w[1*Cn + cch]*xe + V2w[1*Cn + cch]*mv + u1*xv;
            h2 += V1w[2*Cn + cch]*xe + V2w[2*Cn + cch]*mv + u2*xv;
        }
    }
    h0 = fmaxf(h0, 0.f); h1 = fmaxf(h1, 0.f); h2 = fmaxf(h2, 0.f);

    float* opt = out + (size_t)b * (Cn * Tn) + t;
    #pragma unroll
    for (int cch = 0; cch < Cn; ++cch) {
        opt[(size_t)cch * Tn] = Wbias[cch] + Ww[cch*3 + 0]*h0 + Ww[cch*3 + 1]*h1 + Ww[cch*3 + 2]*h2;
    }
}

extern "C" void kernel_launch(void* const* d_in, const int* in_sizes, int n_in,
                              void* d_out, int out_size, void* d_ws, size_t ws_size,
                              hipStream_t stream)
{
    const float* x   = (const float*)d_in[0];
    const float* m   = (const float*)d_in[1];
    const float* d   = (const float*)d_in[2];
    const float* Wf  = (const float*)d_in[3];
    const float* Vf  = (const float*)d_in[4];
    const float* cf  = (const float*)d_in[5];
    const float* Wb  = (const float*)d_in[6];
    const float* Vb  = (const float*)d_in[7];
    const float* cb  = (const float*)d_in[8];
    const float* U   = (const float*)d_in[9];
    const float* c0  = (const float*)d_in[10];
    const float* V1w = (const float*)d_in[11];
    const float* V2w = (const float*)d_in[12];
    const float* Uw  = (const float*)d_in[13];
    const float* Ub  = (const float*)d_in[14];
    const float* Ww  = (const float*)d_in[15];
    const float* Wb_ = (const float*)d_in[16];
    float* out = (float*)d_out;

    // Workspace: accF and accB planes, each T*NS floats (33.5 MB), t-major.
    float* accF = (float*)d_ws;
    float* accB = accF + (size_t)Tn * NS;

    // 4 lanes * 16384 sequences * 2 directions = 131072 threads
    mrnn_scan<<<512, 256, 0, stream>>>(x, m, d, Wf, Vf, cf, Wb, Vb, cb, U, accF, accB);
    // one thread per (b,t) = 131072 threads
    mrnn_mix<<<512, 256, 0, stream>>>(x, m, accF, accB, c0, V1w, V2w, Uw, Ub, Ww, Wb_, out);
}